// Round 1
// baseline (7525.319 us; speedup 1.0000x reference)
//
#include <hip/hip_runtime.h>
#include <hip/hip_bf16.h>
#include <stdint.h>

// Problem constants
#define BATCH 4
#define NPTS  8192
#define KNN   24
#define DPT   32     // D_POINTS
#define DM    64     // D_MODEL
#define PED   60     // PE_DIM
#define DK    (DM*KNN)      // 1536
#define ROWS  (BATCH*NPTS)  // 32768

// ---------------------------------------------------------------------------
// K1: x = features @ W1.T + b1     [ROWS,32] x [64,32]^T -> [ROWS,64]
// ---------------------------------------------------------------------------
__global__ __launch_bounds__(256) void fc1_kernel(
    const float* __restrict__ f, const float* __restrict__ W1,
    const float* __restrict__ b1, float* __restrict__ x) {
  int gid = blockIdx.x * 256 + threadIdx.x;   // ROWS*64 threads
  int n = gid >> 6, c = gid & 63;
  const float* fr = f + (size_t)n * DPT;
  const float* wr = W1 + c * DPT;
  float acc = b1[c];
#pragma unroll
  for (int i = 0; i < DPT; ++i) acc = fmaf(fr[i], wr[i], acc);
  x[(size_t)n * DM + c] = acc;
}

// ---------------------------------------------------------------------------
// K2: exact KNN (top-24 by squared distance, ascending, ties -> lower index)
// One thread per query; u64 key = (f32 dist bits << 32) | candidate index.
// Distances computed in f64 so ordering matches the true/np-f64 ordering.
// ---------------------------------------------------------------------------
__global__ __launch_bounds__(64) void knn_kernel(
    const float* __restrict__ xyz, int* __restrict__ knn) {
  __shared__ float4 tile[64];
  int q = blockIdx.x * 64 + threadIdx.x;      // global query id [0,32768)
  int b = q >> 13;                            // batch
  const float* base = xyz + (size_t)b * NPTS * 3;
  float qx = xyz[(size_t)q * 3 + 0];
  float qy = xyz[(size_t)q * 3 + 1];
  float qz = xyz[(size_t)q * 3 + 2];

  unsigned long long key[KNN];
#pragma unroll
  for (int j = 0; j < KNN; ++j) key[j] = 0x7F800000FFFFFFFFULL;  // +inf
  float lim = __builtin_inff();

  for (int t0 = 0; t0 < NPTS; t0 += 64) {
    int m = t0 + threadIdx.x;
    tile[threadIdx.x] = make_float4(base[(size_t)m * 3 + 0],
                                    base[(size_t)m * 3 + 1],
                                    base[(size_t)m * 3 + 2], 0.f);
    __syncthreads();
#pragma unroll 8
    for (int j = 0; j < 64; ++j) {
      float4 c = tile[j];                      // LDS broadcast (all lanes same addr)
      float dx = qx - c.x, dy = qy - c.y, dz = qz - c.z;
      double dd = (double)dx * (double)dx + (double)dy * (double)dy
                + (double)dz * (double)dz;
      float df = (float)dd;
      if (df < lim) {                          // divergent, rare after warm-up
        unsigned long long v =
            ((unsigned long long)__float_as_uint(df) << 32) | (unsigned)(t0 + j);
#pragma unroll
        for (int s = 0; s < KNN; ++s) {        // stable swap-insert
          bool take = v < key[s];
          unsigned long long old = key[s];
          key[s] = take ? v : key[s];
          v = take ? old : v;
        }
        lim = __uint_as_float((unsigned)(key[KNN - 1] >> 32));
      }
    }
    __syncthreads();
  }
#pragma unroll
  for (int j = 0; j < KNN; ++j)
    knn[(size_t)q * KNN + j] = (int)(unsigned)key[j];   // index relative to batch
}

__device__ __forceinline__ float pe_elem(int t, float gx, float gy, float gz) {
  // pe[60]: per axis a: [sin(g_a*w0..w9), cos(g_a*w0..w9)]
  const float OM[10] = {1.0f, 0.3981071705534972f, 0.15848931924611134f,
                        0.06309573444801933f, 0.025118864315095794f, 0.01f,
                        0.003981071705534973f, 0.001584893192461114f,
                        0.0006309573444801933f, 0.00025118864315095795f};
  int a = t / 20, r = t % 20;
  float g = (a == 0) ? gx : ((a == 1) ? gy : gz);
  float ang = g * OM[r % 10];
  return (r < 10) ? __sinf(ang) : __cosf(ang);
}

// ---------------------------------------------------------------------------
// K3: build pre[n, k*64+c] = q_c - kf_c + pos_enc_c  into the attn region.
// Block = 64 threads = one n; loops k=0..23. Weights staged in LDS (padded).
// ---------------------------------------------------------------------------
__global__ __launch_bounds__(64) void prebuild_kernel(
    const float* __restrict__ xyz, const float* __restrict__ x,
    const int* __restrict__ knn,
    const float* __restrict__ Wd1, const float* __restrict__ bd1,
    const float* __restrict__ Wd2, const float* __restrict__ bd2,
    float* __restrict__ pre) {
  __shared__ float sWd1[DM][PED + 1];
  __shared__ float sWd2[DM][DM + 1];
  __shared__ float sPe[PED];
  __shared__ float sH[DM];
  __shared__ int   sIdx[KNN];
  int n = blockIdx.x, b = n >> 13, tid = threadIdx.x;

  for (int q = tid; q < DM * PED; q += 64) sWd1[q / PED][q % PED] = Wd1[q];
  for (int q = tid; q < DM * DM; q += 64) sWd2[q >> 6][q & 63] = Wd2[q];
  if (tid < KNN) sIdx[tid] = knn[(size_t)n * KNN + tid];
  __syncthreads();

  float qx = xyz[(size_t)n * 3], qy = xyz[(size_t)n * 3 + 1], qz = xyz[(size_t)n * 3 + 2];
  float xq = x[(size_t)n * DM + tid];
  float bd1v = bd1[tid], bd2v = bd2[tid];

  for (int k = 0; k < KNN; ++k) {
    int gidx = (b << 13) + sIdx[k];
    float gx = qx - xyz[(size_t)gidx * 3];
    float gy = qy - xyz[(size_t)gidx * 3 + 1];
    float gz = qz - xyz[(size_t)gidx * 3 + 2];
    if (tid < PED) sPe[tid] = pe_elem(tid, gx, gy, gz);
    __syncthreads();
    float h = bd1v;
#pragma unroll
    for (int j = 0; j < PED; ++j) h = fmaf(sPe[j], sWd1[tid][j], h);
    sH[tid] = fmaxf(h, 0.f);
    __syncthreads();
    float p = bd2v;
#pragma unroll
    for (int o = 0; o < DM; ++o) p = fmaf(sH[o], sWd2[tid][o], p);
    float kfv = x[(size_t)gidx * DM + tid];
    pre[((size_t)n * KNN + k) * DM + tid] = xq - kfv + p;
    __syncthreads();
  }
}

// ---------------------------------------------------------------------------
// K4: logits = pre @ Wa.T + ba.  fp32 SIMT GEMM, 128x128x16 tiles, 8x8/thread.
// Reads from ws chunk copy, writes back to attn region (out-of-place safe).
// ---------------------------------------------------------------------------
#define BM 128
#define BN 128
#define BK 16
__global__ __launch_bounds__(256) void gemm_kernel(
    const float* __restrict__ A,   // chunk rows x DK
    const float* __restrict__ Wa,  // DK x DK
    const float* __restrict__ ba,
    float* __restrict__ C) {       // chunk rows x DK
  __shared__ float As[BK][BM + 4];
  __shared__ float Bs[BK][BN + 4];
  int tid = threadIdx.x;
  int m0 = blockIdx.y * BM, n0 = blockIdx.x * BN;
  int tn = tid & 15, tm = tid >> 4;
  float acc[8][8] = {};

  for (int kt = 0; kt < DK; kt += BK) {
#pragma unroll
    for (int i = 0; i < 2; ++i) {
      int q = tid + i * 256;                 // 512 float4 slots per tile
      int row = q >> 2, c4 = (q & 3) * 4;
      float4 v = *(const float4*)(A + (size_t)(m0 + row) * DK + kt + c4);
      As[c4 + 0][row] = v.x; As[c4 + 1][row] = v.y;
      As[c4 + 2][row] = v.z; As[c4 + 3][row] = v.w;
      float4 w = *(const float4*)(Wa + (size_t)(n0 + row) * DK + kt + c4);
      Bs[c4 + 0][row] = w.x; Bs[c4 + 1][row] = w.y;
      Bs[c4 + 2][row] = w.z; Bs[c4 + 3][row] = w.w;
    }
    __syncthreads();
#pragma unroll
    for (int kk = 0; kk < BK; ++kk) {
      float a[8], bb[8];
      *(float4*)&a[0]  = *(const float4*)&As[kk][tm * 8];
      *(float4*)&a[4]  = *(const float4*)&As[kk][tm * 8 + 4];
      *(float4*)&bb[0] = *(const float4*)&Bs[kk][tn * 8];
      *(float4*)&bb[4] = *(const float4*)&Bs[kk][tn * 8 + 4];
#pragma unroll
      for (int i = 0; i < 8; ++i)
#pragma unroll
        for (int j = 0; j < 8; ++j) acc[i][j] = fmaf(a[i], bb[j], acc[i][j]);
    }
    __syncthreads();
  }
  float bav[8];
#pragma unroll
  for (int j = 0; j < 8; ++j) bav[j] = ba[n0 + tn * 8 + j];
#pragma unroll
  for (int i = 0; i < 8; ++i) {
    float* crow = C + (size_t)(m0 + tm * 8 + i) * DK + n0 + tn * 8;
    float4 o0 = make_float4(acc[i][0] + bav[0], acc[i][1] + bav[1],
                            acc[i][2] + bav[2], acc[i][3] + bav[3]);
    float4 o1 = make_float4(acc[i][4] + bav[4], acc[i][5] + bav[5],
                            acc[i][6] + bav[6], acc[i][7] + bav[7]);
    *(float4*)crow = o0;
    *(float4*)(crow + 4) = o1;
  }
}

// ---------------------------------------------------------------------------
// K5: softmax over K (in-place on attn), recompute pos_enc, einsum over K,
// fc2 + residual -> res.  Block = 64 threads = one n (thread = channel c).
// ---------------------------------------------------------------------------
__global__ __launch_bounds__(64) void finish_kernel(
    const float* __restrict__ xyz, const float* __restrict__ x,
    const int* __restrict__ knn,
    const float* __restrict__ Wd1, const float* __restrict__ bd1,
    const float* __restrict__ Wd2, const float* __restrict__ bd2,
    const float* __restrict__ W2, const float* __restrict__ b2,
    float* __restrict__ attn, float* __restrict__ res) {
  __shared__ float sWd1[DM][PED + 1];
  __shared__ float sWd2[DM][DM + 1];
  __shared__ float sW2[DM][DM + 1];
  __shared__ float sPe[PED];
  __shared__ float sH[DM];
  __shared__ float sRes[DM];
  __shared__ int   sIdx[KNN];
  int n = blockIdx.x, b = n >> 13, c = threadIdx.x;

  for (int q = c; q < DM * PED; q += 64) sWd1[q / PED][q % PED] = Wd1[q];
  for (int q = c; q < DM * DM; q += 64) {
    sWd2[q >> 6][q & 63] = Wd2[q];
    sW2[q >> 6][q & 63] = W2[q];
  }
  if (c < KNN) sIdx[c] = knn[(size_t)n * KNN + c];
  __syncthreads();

  // softmax over k for channel c (scale 1/sqrt(64) = 0.125)
  float L[KNN];
  float mx = -__builtin_inff();
#pragma unroll
  for (int k = 0; k < KNN; ++k) {
    L[k] = attn[((size_t)n * KNN + k) * DM + c];
    mx = fmaxf(mx, L[k]);
  }
  float ssum = 0.f;
#pragma unroll
  for (int k = 0; k < KNN; ++k) { L[k] = __expf((L[k] - mx) * 0.125f); ssum += L[k]; }
  float inv = 1.0f / ssum;
#pragma unroll
  for (int k = 0; k < KNN; ++k) {
    L[k] *= inv;
    attn[((size_t)n * KNN + k) * DM + c] = L[k];
  }

  float qx = xyz[(size_t)n * 3], qy = xyz[(size_t)n * 3 + 1], qz = xyz[(size_t)n * 3 + 2];
  float bd1v = bd1[c], bd2v = bd2[c];
  float racc = 0.f;
  for (int k = 0; k < KNN; ++k) {
    int gidx = (b << 13) + sIdx[k];
    float gx = qx - xyz[(size_t)gidx * 3];
    float gy = qy - xyz[(size_t)gidx * 3 + 1];
    float gz = qz - xyz[(size_t)gidx * 3 + 2];
    if (c < PED) sPe[c] = pe_elem(c, gx, gy, gz);
    __syncthreads();
    float h = bd1v;
#pragma unroll
    for (int j = 0; j < PED; ++j) h = fmaf(sPe[j], sWd1[c][j], h);
    sH[c] = fmaxf(h, 0.f);
    __syncthreads();
    float p = bd2v;
#pragma unroll
    for (int o = 0; o < DM; ++o) p = fmaf(sH[o], sWd2[c][o], p);
    float vpe = x[(size_t)gidx * DM + c] + p;
    racc = fmaf(L[k], vpe, racc);
    __syncthreads();
  }
  sRes[c] = racc;
  __syncthreads();
  float oacc = b2[c] + x[(size_t)n * DM + c];
#pragma unroll
  for (int o = 0; o < DM; ++o) oacc = fmaf(sRes[o], sW2[c][o], oacc);
  res[(size_t)n * DM + c] = oacc;
}

// ---------------------------------------------------------------------------
extern "C" void kernel_launch(void* const* d_in, const int* in_sizes, int n_in,
                              void* d_out, int out_size, void* d_ws, size_t ws_size,
                              hipStream_t stream) {
  const float* features = (const float*)d_in[0];
  const float* xyz = (const float*)d_in[1];
  const float* W1  = (const float*)d_in[2];
  const float* b1  = (const float*)d_in[3];
  const float* W2  = (const float*)d_in[4];
  const float* b2  = (const float*)d_in[5];
  const float* Wd1 = (const float*)d_in[6];
  const float* bd1 = (const float*)d_in[7];
  const float* Wd2 = (const float*)d_in[8];
  const float* bd2 = (const float*)d_in[9];
  const float* Wa  = (const float*)d_in[10];
  const float* ba  = (const float*)d_in[11];

  float* res  = (float*)d_out;                    // [ROWS*64]
  float* attn = (float*)d_out + (size_t)ROWS * DM;  // [ROWS*1536] (pre/logits/attn)

  float* xbuf = (float*)d_ws;                                        // 8 MB
  int*   knn  = (int*)((char*)d_ws + (size_t)ROWS * DM * 4);         // 3 MB
  char*  chunkbuf = (char*)d_ws + (size_t)ROWS * DM * 4 + (size_t)ROWS * KNN * 4;
  size_t used = (size_t)ROWS * DM * 4 + (size_t)ROWS * KNN * 4;
  size_t avail = (ws_size > used) ? ws_size - used : 0;
  size_t rowbytes = (size_t)DK * 4;
  long long cr_ll = (long long)(avail / rowbytes);
  int chunk_rows = (cr_ll > ROWS) ? ROWS : (int)cr_ll;
  chunk_rows &= ~127;                    // multiple of BM
  if (chunk_rows < 128) chunk_rows = 128;  // trust minimal ws

  hipLaunchKernelGGL(fc1_kernel, dim3(ROWS * DM / 256), dim3(256), 0, stream,
                     features, W1, b1, xbuf);
  hipLaunchKernelGGL(knn_kernel, dim3(ROWS / 64), dim3(64), 0, stream, xyz, knn);
  hipLaunchKernelGGL(prebuild_kernel, dim3(ROWS), dim3(64), 0, stream,
                     xyz, xbuf, knn, Wd1, bd1, Wd2, bd2, attn);
  for (int r0 = 0; r0 < ROWS; r0 += chunk_rows) {
    int cr = (ROWS - r0 < chunk_rows) ? (ROWS - r0) : chunk_rows;
    hipMemcpyAsync(chunkbuf, attn + (size_t)r0 * DK, (size_t)cr * rowbytes,
                   hipMemcpyDeviceToDevice, stream);
    hipLaunchKernelGGL(gemm_kernel, dim3(DK / BN, cr / BM), dim3(256), 0, stream,
                       (const float*)chunkbuf, Wa, ba, attn + (size_t)r0 * DK);
  }
  hipLaunchKernelGGL(finish_kernel, dim3(ROWS), dim3(64), 0, stream,
                     xyz, xbuf, knn, Wd1, bd1, Wd2, bd2, W2, b2, attn, res);
}

// Round 2
// 3328.862 us; speedup vs baseline: 2.2606x; 2.2606x over previous
//
#include <hip/hip_runtime.h>
#include <hip/hip_bf16.h>
#include <stdint.h>

// Problem constants
#define BATCH 4
#define NPTS  8192
#define KNN   24
#define DPT   32     // D_POINTS
#define DM    64     // D_MODEL
#define PED   60     // PE_DIM
#define DK    (DM*KNN)      // 1536
#define ROWS  (BATCH*NPTS)  // 32768

typedef __attribute__((ext_vector_type(8))) short short8;
typedef __attribute__((ext_vector_type(4))) float f32x4;
typedef __attribute__((address_space(3))) unsigned lds_u32;
typedef const __attribute__((address_space(1))) unsigned gbl_u32;

#define WSYNC() __builtin_amdgcn_wave_barrier()

static __device__ __forceinline__ unsigned short f2bf(float f) {
  __hip_bfloat16 h = __float2bfloat16(f);
  return *(unsigned short*)&h;
}

// ---------------------------------------------------------------------------
// K1: x = features @ W1.T + b1     [ROWS,32] x [64,32]^T -> [ROWS,64]
// ---------------------------------------------------------------------------
__global__ __launch_bounds__(256) void fc1_kernel(
    const float* __restrict__ f, const float* __restrict__ W1,
    const float* __restrict__ b1, float* __restrict__ x) {
  int gid = blockIdx.x * 256 + threadIdx.x;
  int n = gid >> 6, c = gid & 63;
  const float* fr = f + (size_t)n * DPT;
  const float* wr = W1 + c * DPT;
  float acc = b1[c];
#pragma unroll
  for (int i = 0; i < DPT; ++i) acc = fmaf(fr[i], wr[i], acc);
  x[(size_t)n * DM + c] = acc;
}

// ---------------------------------------------------------------------------
// K2: exact KNN, 2-way candidate split. Block = 256 thr = 128 queries x 2 segs.
// Wave = uniform segment -> candidate loads become scalar (s_load broadcast).
// Distance arithmetic identical to round 1 (f32 diff, f64 squares): verified
// to reproduce the reference top_k ordering.
// ---------------------------------------------------------------------------
__global__ __launch_bounds__(256) void knn_kernel(
    const float* __restrict__ xyz, int* __restrict__ knn) {
  __shared__ unsigned long long sKeys[256][KNN];   // 48 KB
  int tid = threadIdx.x;
  int ql = tid & 127;            // query in block
  int s  = tid >> 7;             // segment 0/1 (wave-uniform)
  int q  = blockIdx.x * 128 + ql;
  int b  = q >> 13;

  int segoff = b * NPTS * 3 + s * (NPTS / 2) * 3;
  segoff = __builtin_amdgcn_readfirstlane(segoff);   // force SGPR base
  const float* seg = xyz + segoff;

  float qx = xyz[(size_t)q * 3 + 0];
  float qy = xyz[(size_t)q * 3 + 1];
  float qz = xyz[(size_t)q * 3 + 2];

  unsigned long long key[KNN];
#pragma unroll
  for (int j = 0; j < KNN; ++j) key[j] = 0x7F800000FFFFFFFFULL;
  float lim = __builtin_inff();
  int idx0 = s * (NPTS / 2);

#pragma unroll 4
  for (int m = 0; m < NPTS / 2; ++m) {
    float cx = seg[3 * m + 0];
    float cy = seg[3 * m + 1];
    float cz = seg[3 * m + 2];
    float dx = qx - cx, dy = qy - cy, dz = qz - cz;
    double dd = (double)dx * (double)dx + (double)dy * (double)dy
              + (double)dz * (double)dz;
    float df = (float)dd;
    if (df < lim) {
      unsigned long long v =
          ((unsigned long long)__float_as_uint(df) << 32) | (unsigned)(idx0 + m);
#pragma unroll
      for (int t = 0; t < KNN; ++t) {
        bool take = v < key[t];
        unsigned long long old = key[t];
        key[t] = take ? v : key[t];
        v = take ? old : v;
      }
      lim = __uint_as_float((unsigned)(key[KNN - 1] >> 32));
    }
  }
#pragma unroll
  for (int j = 0; j < KNN; ++j) sKeys[tid][j] = key[j];
  __syncthreads();

  if (tid < 128) {               // merge two sorted 24-lists -> smallest 24
    int qq = blockIdx.x * 128 + tid;
    int i = 0, j = 0;
    for (int o = 0; o < KNN; ++o) {
      unsigned long long a = sKeys[tid][i];
      unsigned long long c = sKeys[tid + 128][j];
      bool ta = a < c;
      knn[(size_t)qq * KNN + o] = (int)(unsigned)(ta ? a : c);
      if (ta) ++i; else ++j;
    }
  }
}

// ---------------------------------------------------------------------------
__device__ __forceinline__ float pe_elem(int t, float gx, float gy, float gz) {
  const float OM[10] = {1.0f, 0.3981071705534972f, 0.15848931924611134f,
                        0.06309573444801933f, 0.025118864315095794f, 0.01f,
                        0.003981071705534973f, 0.001584893192461114f,
                        0.0006309573444801933f, 0.00025118864315095795f};
  int a = t / 20, r = t % 20;
  float g = (a == 0) ? gx : ((a == 1) ? gy : gz);
  float ang = g * OM[r % 10];
  return (r < 10) ? __sinf(ang) : __cosf(ang);
}

// ---------------------------------------------------------------------------
// K3: pre[n, k*64+c] = q_c - kf_c + pos_enc_c  (f32, into attn region).
// Block 256 = 4 queries, one per wave; Wd1/Wd2 rows in registers; wave-sync.
// ---------------------------------------------------------------------------
__global__ __launch_bounds__(256) void prebuild_kernel(
    const float* __restrict__ xyz, const float* __restrict__ x,
    const int* __restrict__ knn,
    const float* __restrict__ Wd1, const float* __restrict__ bd1,
    const float* __restrict__ Wd2, const float* __restrict__ bd2,
    float* __restrict__ pre) {
  __shared__ float sPe[4][64];
  __shared__ float sH[4][64];
  __shared__ int   sIdx[4][KNN];
  int tid = threadIdx.x, w = tid >> 6, c = tid & 63;
  int n = blockIdx.x * 4 + w, b = n >> 13;

  float wd1r[PED], wd2r[DM];
#pragma unroll
  for (int j = 0; j < PED; ++j) wd1r[j] = Wd1[c * PED + j];
#pragma unroll
  for (int o = 0; o < DM; ++o) wd2r[o] = Wd2[c * DM + o];

  if (c < KNN) sIdx[w][c] = knn[(size_t)n * KNN + c];
  float qx = xyz[(size_t)n * 3], qy = xyz[(size_t)n * 3 + 1], qz = xyz[(size_t)n * 3 + 2];
  float xq = x[(size_t)n * DM + c];
  float bd1v = bd1[c], bd2v = bd2[c];
  WSYNC();

  for (int k = 0; k < KNN; ++k) {
    int gidx = (b << 13) + sIdx[w][k];
    float gx = qx - xyz[(size_t)gidx * 3];
    float gy = qy - xyz[(size_t)gidx * 3 + 1];
    float gz = qz - xyz[(size_t)gidx * 3 + 2];
    if (c < PED) sPe[w][c] = pe_elem(c, gx, gy, gz);
    WSYNC();
    float h = bd1v;
    const float4* p4 = (const float4*)&sPe[w][0];
#pragma unroll
    for (int jj = 0; jj < 15; ++jj) {
      float4 pv = p4[jj];
      h = fmaf(pv.x, wd1r[4 * jj + 0], h);
      h = fmaf(pv.y, wd1r[4 * jj + 1], h);
      h = fmaf(pv.z, wd1r[4 * jj + 2], h);
      h = fmaf(pv.w, wd1r[4 * jj + 3], h);
    }
    sH[w][c] = fmaxf(h, 0.f);
    WSYNC();
    float p = bd2v;
    const float4* h4 = (const float4*)&sH[w][0];
#pragma unroll
    for (int oo = 0; oo < 16; ++oo) {
      float4 hv = h4[oo];
      p = fmaf(hv.x, wd2r[4 * oo + 0], p);
      p = fmaf(hv.y, wd2r[4 * oo + 1], p);
      p = fmaf(hv.z, wd2r[4 * oo + 2], p);
      p = fmaf(hv.w, wd2r[4 * oo + 3], p);
    }
    float kfv = x[(size_t)gidx * DM + c];
    pre[((size_t)n * KNN + k) * DM + c] = xq - kfv + p;
    WSYNC();
  }
}

// ---------------------------------------------------------------------------
// K4a: f32 -> bf16 convert (vectorized)
// ---------------------------------------------------------------------------
__global__ __launch_bounds__(256) void conv_bf16_kernel(
    const float* __restrict__ src, unsigned short* __restrict__ dst, int n4) {
  int i = blockIdx.x * 256 + threadIdx.x;
  if (i < n4) {
    float4 v = ((const float4*)src)[i];
    ushort4 o;
    o.x = f2bf(v.x); o.y = f2bf(v.y); o.z = f2bf(v.z); o.w = f2bf(v.w);
    ((ushort4*)dst)[i] = o;
  }
}

// ---------------------------------------------------------------------------
// K4b: logits = pre_bf16 @ Wa_bf16.T + ba  via MFMA 16x16x32, 128x128 tiles,
// global_load_lds width-16, frag-major LDS (lane-contiguous ds_read_b128).
// ---------------------------------------------------------------------------
__global__ __launch_bounds__(256) void gemm_bf16_kernel(
    const unsigned short* __restrict__ A,   // [cr][1536] bf16
    const unsigned short* __restrict__ B,   // Wa bf16 [1536][1536]
    const float* __restrict__ ba,
    float* __restrict__ C) {                // [cr][1536] f32
  __shared__ unsigned short sA[8 * 512];    // 8 KB: unit u=mb*64+lane, 8 bf16/unit
  __shared__ unsigned short sB[8 * 512];
  int tid = threadIdx.x, w = tid >> 6, L = tid & 63;
  int m0 = blockIdx.y * 128, n0 = blockIdx.x * 128;
  int wr = w >> 1, wc = w & 1;
  int lrow = L & 15, lq = L >> 4;           // frag row / k-quad

  f32x4 acc[4][4];
#pragma unroll
  for (int i = 0; i < 4; ++i)
#pragma unroll
    for (int j = 0; j < 4; ++j) acc[i][j] = (f32x4){0.f, 0.f, 0.f, 0.f};

  for (int kt = 0; kt < DK; kt += 32) {
#pragma unroll
    for (int i = 0; i < 2; ++i) {
      int tb = w * 2 + i;                   // 0..7: 16-row block
      const unsigned short* ga = A + ((size_t)(m0 + tb * 16 + lrow)) * DK + kt + lq * 8;
      __builtin_amdgcn_global_load_lds((gbl_u32*)ga, (lds_u32*)(sA + tb * 512), 16, 0, 0);
      const unsigned short* gb = B + ((size_t)(n0 + tb * 16 + lrow)) * DK + kt + lq * 8;
      __builtin_amdgcn_global_load_lds((gbl_u32*)gb, (lds_u32*)(sB + tb * 512), 16, 0, 0);
    }
    __syncthreads();
    short8 af[4], bf[4];
#pragma unroll
    for (int i = 0; i < 4; ++i)
      af[i] = *(const short8*)(sA + ((wr * 4 + i) * 64 + L) * 8);
#pragma unroll
    for (int j = 0; j < 4; ++j)
      bf[j] = *(const short8*)(sB + ((wc * 4 + j) * 64 + L) * 8);
#pragma unroll
    for (int i = 0; i < 4; ++i)
#pragma unroll
      for (int j = 0; j < 4; ++j)
        acc[i][j] = __builtin_amdgcn_mfma_f32_16x16x32_bf16(af[i], bf[j], acc[i][j], 0, 0, 0);
    __syncthreads();
  }
  // epilogue: C row = m0+(wr*4+i)*16 + lq*4 + r, col = n0+(wc*4+j)*16 + lrow
#pragma unroll
  for (int j = 0; j < 4; ++j) {
    int col = n0 + (wc * 4 + j) * 16 + lrow;
    float bav = ba[col];
#pragma unroll
    for (int i = 0; i < 4; ++i) {
      int rbase = m0 + (wr * 4 + i) * 16 + lq * 4;
#pragma unroll
      for (int r = 0; r < 4; ++r)
        C[(size_t)(rbase + r) * DK + col] = acc[i][j][r] + bav;
    }
  }
}

// ---------------------------------------------------------------------------
// K5: softmax over K, recompute pos_enc, einsum, fc2 + residual.
// Block 256 = 4 queries (one per wave), wave-sync k-loop, weights in LDS.
// ---------------------------------------------------------------------------
__global__ __launch_bounds__(256) void finish_kernel(
    const float* __restrict__ xyz, const float* __restrict__ x,
    const int* __restrict__ knn,
    const float* __restrict__ Wd1, const float* __restrict__ bd1,
    const float* __restrict__ Wd2, const float* __restrict__ bd2,
    const float* __restrict__ W2, const float* __restrict__ b2,
    float* __restrict__ attn, float* __restrict__ res) {
  __shared__ float sWd1[DM][PED + 1];
  __shared__ float sWd2[DM][DM + 1];
  __shared__ float sW2[DM][DM + 1];
  __shared__ float sPe[4][64];
  __shared__ float sH[4][64];
  __shared__ float sRes[4][64];
  __shared__ int   sIdx[4][KNN];
  int tid = threadIdx.x, w = tid >> 6, c = tid & 63;
  int n = blockIdx.x * 4 + w, b = n >> 13;

  for (int q = tid; q < DM * PED; q += 256) sWd1[q / PED][q % PED] = Wd1[q];
  for (int q = tid; q < DM * DM; q += 256) {
    sWd2[q >> 6][q & 63] = Wd2[q];
    sW2[q >> 6][q & 63] = W2[q];
  }
  if (c < KNN) sIdx[w][c] = knn[(size_t)n * KNN + c];
  __syncthreads();

  float L[KNN];
  float mx = -__builtin_inff();
#pragma unroll
  for (int k = 0; k < KNN; ++k) {
    L[k] = attn[((size_t)n * KNN + k) * DM + c];
    mx = fmaxf(mx, L[k]);
  }
  float ssum = 0.f;
#pragma unroll
  for (int k = 0; k < KNN; ++k) { L[k] = __expf((L[k] - mx) * 0.125f); ssum += L[k]; }
  float inv = 1.0f / ssum;
#pragma unroll
  for (int k = 0; k < KNN; ++k) {
    L[k] *= inv;
    attn[((size_t)n * KNN + k) * DM + c] = L[k];
  }

  float qx = xyz[(size_t)n * 3], qy = xyz[(size_t)n * 3 + 1], qz = xyz[(size_t)n * 3 + 2];
  float bd1v = bd1[c], bd2v = bd2[c];
  float racc = 0.f;
  for (int k = 0; k < KNN; ++k) {
    int gidx = (b << 13) + sIdx[w][k];
    float gx = qx - xyz[(size_t)gidx * 3];
    float gy = qy - xyz[(size_t)gidx * 3 + 1];
    float gz = qz - xyz[(size_t)gidx * 3 + 2];
    if (c < PED) sPe[w][c] = pe_elem(c, gx, gy, gz);
    WSYNC();
    float h = bd1v;
#pragma unroll
    for (int j = 0; j < PED; ++j) h = fmaf(sPe[w][j], sWd1[c][j], h);
    sH[w][c] = fmaxf(h, 0.f);
    WSYNC();
    float p = bd2v;
#pragma unroll
    for (int o = 0; o < DM; ++o) p = fmaf(sH[w][o], sWd2[c][o], p);
    racc = fmaf(L[k], x[(size_t)gidx * DM + c] + p, racc);
    WSYNC();
  }
  sRes[w][c] = racc;
  WSYNC();
  float oacc = b2[c] + x[(size_t)n * DM + c];
#pragma unroll
  for (int o = 0; o < DM; ++o) oacc = fmaf(sRes[w][o], sW2[c][o], oacc);
  res[(size_t)n * DM + c] = oacc;
}

// ---------------------------------------------------------------------------
extern "C" void kernel_launch(void* const* d_in, const int* in_sizes, int n_in,
                              void* d_out, int out_size, void* d_ws, size_t ws_size,
                              hipStream_t stream) {
  const float* features = (const float*)d_in[0];
  const float* xyz = (const float*)d_in[1];
  const float* W1  = (const float*)d_in[2];
  const float* b1  = (const float*)d_in[3];
  const float* W2  = (const float*)d_in[4];
  const float* b2  = (const float*)d_in[5];
  const float* Wd1 = (const float*)d_in[6];
  const float* bd1 = (const float*)d_in[7];
  const float* Wd2 = (const float*)d_in[8];
  const float* bd2 = (const float*)d_in[9];
  const float* Wa  = (const float*)d_in[10];
  const float* ba  = (const float*)d_in[11];

  float* res  = (float*)d_out;                      // [ROWS*64]
  float* attn = (float*)d_out + (size_t)ROWS * DM;  // [ROWS*1536] pre/logits/attn

  size_t xB   = (size_t)ROWS * DM * 4;              // 8,388,608
  size_t knnB = (size_t)ROWS * KNN * 4;             // 3,145,728
  size_t WaB  = (size_t)DK * DK * 2;                // 4,718,592
  size_t used = xB + knnB;                          // proven ws >= ~12 MB (round 1)
  float* xbuf = (float*)d_ws;
  int*   knn  = (int*)((char*)d_ws + xB);

  unsigned short *WaBf, *chunk;
  int chunk_rows;
  size_t avail = (ws_size > used) ? ws_size - used : 0;
  size_t rowB = (size_t)DK * 2;
  if (avail >= WaB + 128 * rowB) {                  // scratch fits in ws
    WaBf  = (unsigned short*)((char*)d_ws + used);
    chunk = (unsigned short*)((char*)d_ws + used + WaB);
    size_t cr = (avail - WaB) / rowB;
    chunk_rows = (cr > ROWS) ? ROWS : (int)cr;
    chunk_rows &= ~127;
  } else {                                          // fallback: res region scratch
    WaBf  = (unsigned short*)d_out;
    chunk = (unsigned short*)((char*)d_out + WaB);
    chunk_rows = (int)((xB - WaB) / rowB) & ~127;   // 1152
  }

  hipLaunchKernelGGL(fc1_kernel, dim3(ROWS * DM / 256), dim3(256), 0, stream,
                     features, W1, b1, xbuf);
  hipLaunchKernelGGL(knn_kernel, dim3(ROWS / 128), dim3(256), 0, stream, xyz, knn);
  hipLaunchKernelGGL(prebuild_kernel, dim3(ROWS / 4), dim3(256), 0, stream,
                     xyz, xbuf, knn, Wd1, bd1, Wd2, bd2, attn);
  {
    int n4 = DK * DK / 4;
    hipLaunchKernelGGL(conv_bf16_kernel, dim3((n4 + 255) / 256), dim3(256), 0, stream,
                       Wa, WaBf, n4);
  }
  for (int r0 = 0; r0 < ROWS; r0 += chunk_rows) {
    int cr = (ROWS - r0 < chunk_rows) ? (ROWS - r0) : chunk_rows;
    int n4 = cr * DK / 4;
    hipLaunchKernelGGL(conv_bf16_kernel, dim3((n4 + 255) / 256), dim3(256), 0, stream,
                       attn + (size_t)r0 * DK, chunk, n4);
    hipLaunchKernelGGL(gemm_bf16_kernel, dim3(DK / 128, cr / 128), dim3(256), 0, stream,
                       chunk, WaBf, ba, attn + (size_t)r0 * DK);
  }
  hipLaunchKernelGGL(finish_kernel, dim3(ROWS / 4), dim3(256), 0, stream,
                     xyz, xbuf, knn, Wd1, bd1, Wd2, bd2, W2, b2, attn, res);
}